// Round 3
// baseline (182.091 us; speedup 1.0000x reference)
//
#include <hip/hip_runtime.h>
#include <stdint.h>

#define BM 128
#define BN 128
#define KD 256     // K dimension; kernel assumes 256

typedef __attribute__((ext_vector_type(4))) float f32x4;
typedef __attribute__((ext_vector_type(4))) int   i32x4;
typedef __attribute__((ext_vector_type(8))) int   i32x8;

// Kernel 1: per-row normalize, convert to fp8 e4m3 (OCP HW cvt); fp32 diag.
// Lane l handles elements [4l, 4l+4). Also zeroes d_out.
__global__ __launch_bounds__(256) void norm_kernel(
    const float* __restrict__ a, const float* __restrict__ b,
    unsigned int* __restrict__ an, unsigned int* __restrict__ bn,
    float* __restrict__ diag, float* __restrict__ out, int D) {
  if (blockIdx.x == 0 && threadIdx.x == 0) out[0] = 0.f;
  const int row = blockIdx.x * 4 + (threadIdx.x >> 6);
  const int l = threadIdx.x & 63;
  const float4 av = ((const float4*)(a + (size_t)row * D))[l];
  const float4 bv = ((const float4*)(b + (size_t)row * D))[l];
  float ssa = av.x*av.x + av.y*av.y + av.z*av.z + av.w*av.w;
  float ssb = bv.x*bv.x + bv.y*bv.y + bv.z*bv.z + bv.w*bv.w;
  float dot = av.x*bv.x + av.y*bv.y + av.z*bv.z + av.w*bv.w;
  for (int off = 1; off < 64; off <<= 1) {
    ssa += __shfl_xor(ssa, off, 64);
    ssb += __shfl_xor(ssb, off, 64);
    dot += __shfl_xor(dot, off, 64);
  }
  const float inva = 1.0f / sqrtf(ssa);
  const float invb = 1.0f / sqrtf(ssb);
  if (l == 0) diag[row] = dot * inva * invb;
  int pa = 0, pb = 0;
  pa = __builtin_amdgcn_cvt_pk_fp8_f32(av.x * inva, av.y * inva, pa, 0);
  pa = __builtin_amdgcn_cvt_pk_fp8_f32(av.z * inva, av.w * inva, pa, 1);
  pb = __builtin_amdgcn_cvt_pk_fp8_f32(bv.x * invb, bv.y * invb, pb, 0);
  pb = __builtin_amdgcn_cvt_pk_fp8_f32(bv.z * invb, bv.w * invb, pb, 1);
  an[(size_t)row * (D / 4) + l] = (unsigned int)pa;
  bn[(size_t)row * (D / 4) + l] = (unsigned int)pb;
}

// Kernel 2: PERSISTENT-BLOCK fp8 GEMM+max. Grid = 256 blocks (1/CU), 512
// threads (8 waves, 2/SIMD). Block p owns tj = p&63 (B-panel, staged ONCE,
// 32 KB) and iterates 16 A-panels ti = (p>>6) + 4k with a 2x32 KB double
// buffer: issue next panel's global_load_lds BEFORE compute; the single
// end-of-iteration __syncthreads' vmcnt drain overlaps the whole compute.
// One barrier per iteration, zero mid-iteration barriers: row reduction is
// an fr-butterfly (shfl_xor 1/2/4/8), stored per (tj,wn) slot (256 row
// slots); col partials accumulate in REGISTERS across all 16 tiles (tj
// fixed) and are written once at the end.
// Wave (wm,wn) = (w>>2, w&3) owns a 64x32 output sub-tile: acc[4][2].
// XOR swizzle at 16B-chunk granularity: stored position of chunk c of row
// r = ((c&7)^(r&7))|(c&8), applied on the GLOBAL source side; read offsets
// p0/p1 pick chunks 2hi/2hi+1 conflict-free (same scheme as prior rounds).
__global__ __launch_bounds__(512, 2) void gemm_max_kernel(
    const unsigned char* __restrict__ an, const unsigned char* __restrict__ bn,
    const int* __restrict__ labels,
    float* __restrict__ row_part, float* __restrict__ col_part, int B) {
  __shared__ __align__(16) unsigned char sA[2 * BM * KD];  // 64 KB dbuf
  __shared__ __align__(16) unsigned char sB[BN * KD];      // 32 KB
  __shared__ float lds_col[2][BN];                         // 1 KB

  const int tid  = threadIdx.x;
  const int lane = tid & 63;
  const int w    = tid >> 6;            // 0..7
  const int wm   = w >> 2, wn = w & 3;
  const int g0   = blockIdx.x >> 6;     // 0..3 : ti = g0 + 4k
  const int tj   = blockIdx.x & 63;     // fixed B-panel

  // staging decomposition: per pass each wave stages 4 rows x 16 chunks
  const int sr = lane >> 4;             // row within 4-row group
  const int sc = lane & 15;             // dest 16B-chunk position

  // fragment decomposition
  const int fr = lane & 15;             // m/n index
  const int hi = lane >> 4;             // k-quad
  const int p0 = ((2 * hi)     ^ (fr & 7)) * 16;
  const int p1 = ((2 * hi + 1) ^ (fr & 7)) * 16;

  // ---- Prologue: stage B (once) + A panel 0 ----
  #pragma unroll
  for (int pass = 0; pass < 4; ++pass) {
    const int r0  = pass * 32 + w * 4;
    const int row = r0 + sr;
    const int g = ((sc & 7) ^ (row & 7)) | (sc & 8);
    const unsigned char* gb = bn + (size_t)(tj * BN + row) * KD + g * 16;
    const unsigned char* ga = an + (size_t)(g0 * BM + row) * KD + g * 16;
    __builtin_amdgcn_global_load_lds(
        (const __attribute__((address_space(1))) void*)gb,
        (__attribute__((address_space(3))) void*)(sB + r0 * KD + lane * 16), 16, 0, 0);
    __builtin_amdgcn_global_load_lds(
        (const __attribute__((address_space(1))) void*)ga,
        (__attribute__((address_space(3))) void*)(sA + r0 * KD + lane * 16), 16, 0, 0);
  }
  __syncthreads();

  int labc[2];
  labc[0] = labels[tj * BN + wn * 32 + fr];
  labc[1] = labels[tj * BN + wn * 32 + 16 + fr];

  const int SC = 0x7F7F7F7F;            // E8M0 = 1.0 in all byte slots
  float cp[2] = {-1e9f, -1e9f};         // col partials, live across all k
  int bsel = 0;

  for (int k = 0; k < 16; ++k) {
    const int ti = g0 + 4 * k;

    // Issue next A-panel stage into the other buffer (overlaps compute).
    if (k < 15) {
      const int tin = g0 + 4 * (k + 1);
      #pragma unroll
      for (int pass = 0; pass < 4; ++pass) {
        const int r0  = pass * 32 + w * 4;
        const int row = r0 + sr;
        const int g = ((sc & 7) ^ (row & 7)) | (sc & 8);
        const unsigned char* ga = an + (size_t)(tin * BM + row) * KD + g * 16;
        __builtin_amdgcn_global_load_lds(
            (const __attribute__((address_space(1))) void*)ga,
            (__attribute__((address_space(3))) void*)
                (sA + (bsel ^ 1) * (BM * KD) + r0 * KD + lane * 16), 16, 0, 0);
      }
    }

    // ---- Compute 16 MFMAs from sA[bsel] + sB ----
    f32x4 acc[4][2];
    #pragma unroll
    for (int mt = 0; mt < 4; ++mt) {
      acc[mt][0] = (f32x4){0.f, 0.f, 0.f, 0.f};
      acc[mt][1] = (f32x4){0.f, 0.f, 0.f, 0.f};
    }
    const unsigned char* Ab = sA + bsel * (BM * KD);
    #pragma unroll
    for (int it = 0; it < 2; ++it) {
      i32x8 bf[2];
      #pragma unroll
      for (int nt = 0; nt < 2; ++nt) {
        const unsigned char* rb = sB + (wn * 32 + nt * 16 + fr) * KD + it * 128;
        bf[nt] = __builtin_shufflevector(*(const i32x4*)(rb + p0),
                                         *(const i32x4*)(rb + p1),
                                         0, 1, 2, 3, 4, 5, 6, 7);
      }
      #pragma unroll
      for (int mt = 0; mt < 4; ++mt) {
        const unsigned char* ra = Ab + (wm * 64 + mt * 16 + fr) * KD + it * 128;
        i32x8 af = __builtin_shufflevector(*(const i32x4*)(ra + p0),
                                           *(const i32x4*)(ra + p1),
                                           0, 1, 2, 3, 4, 5, 6, 7);
        acc[mt][0] = __builtin_amdgcn_mfma_scale_f32_16x16x128_f8f6f4(
            af, bf[0], acc[mt][0], 0, 0, 0, SC, 0, SC);
        acc[mt][1] = __builtin_amdgcn_mfma_scale_f32_16x16x128_f8f6f4(
            af, bf[1], acc[mt][1], 0, 0, 0, SC, 0, SC);
      }
    }

    // ---- Epilogue for this tile (no barrier) ----
    int li[4][4];
    #pragma unroll
    for (int mt = 0; mt < 4; ++mt)
      #pragma unroll
      for (int r = 0; r < 4; ++r)
        li[mt][r] = labels[ti * BM + wm * 64 + mt * 16 + hi * 4 + r];

    const size_t rowbase =
        (size_t)(tj * 4 + wn) * B + (size_t)ti * BM + wm * 64;
    #pragma unroll
    for (int mt = 0; mt < 4; ++mt) {
      float rr4[4];
      #pragma unroll
      for (int r = 0; r < 4; ++r) {
        const int l0 = li[mt][r];
        const float vm0 = (l0 != labc[0]) ? acc[mt][0][r] : -1e9f;
        const float vm1 = (l0 != labc[1]) ? acc[mt][1][r] : -1e9f;
        cp[0] = fmaxf(cp[0], vm0);
        cp[1] = fmaxf(cp[1], vm1);
        float rm = fmaxf(vm0, vm1);
        rm = fmaxf(rm, __shfl_xor(rm, 1, 64));
        rm = fmaxf(rm, __shfl_xor(rm, 2, 64));
        rm = fmaxf(rm, __shfl_xor(rm, 4, 64));
        rm = fmaxf(rm, __shfl_xor(rm, 8, 64));
        rr4[r] = rm;
      }
      // one lane per hi-group stores 4 consecutive rows as float4
      if (fr == mt) {
        f32x4 v = {rr4[0], rr4[1], rr4[2], rr4[3]};
        *(f32x4*)(row_part + rowbase + mt * 16 + hi * 4) = v;
      }
    }

    __syncthreads();   // drains vmcnt: next A-panel staged; sA[bsel] reads done
    bsel ^= 1;
  }

  // ---- Col partials: reduce across hi lanes, then across wm via LDS ----
  #pragma unroll
  for (int nt = 0; nt < 2; ++nt) {
    float c = cp[nt];
    c = fmaxf(c, __shfl_xor(c, 16, 64));
    c = fmaxf(c, __shfl_xor(c, 32, 64));
    if (hi == 0) lds_col[wm][wn * 32 + nt * 16 + fr] = c;
  }
  __syncthreads();
  if (tid < BN)
    col_part[(size_t)g0 * B + tj * BN + tid] =
        fmaxf(lds_col[0][tid], lds_col[1][tid]);
}

// Kernel 3: reduce per-tile maxes -> M; hard-negative threshold + pos_valid;
// per-row loss; one float atomicAdd of blocksum/B into d_out (zeroed by norm).
// Row direction has Tr=256 slots (tj x wn), col direction Tc=4 (g0).
__global__ __launch_bounds__(256) void finalize_kernel(
    const float* __restrict__ row_part, const float* __restrict__ col_part,
    const float* __restrict__ diag, int B, int Tr, int Tc,
    float* __restrict__ out) {
  const int v = blockIdx.x * 256 + threadIdx.x;
  const bool isrow = v < B;
  const int i = isrow ? v : v - B;
  const float* part = isrow ? row_part : col_part;
  const int T = isrow ? Tr : Tc;
  float m = -1e9f;
  for (int t = 0; t < T; ++t) m = fmaxf(m, part[(size_t)t * B + i]);
  const float d = diag[i];
  float loss = 0.f;
  if ((d < 1.0f - 1e-5f) && (m + 0.2f > d)) {
    loss = fmaxf(0.2f * d * d - 0.7f * d + 0.5f, 0.f) +
           fmaxf(0.9f * m * m - 0.4f * m + 0.03f, 0.f);
  }
  for (int off = 1; off < 64; off <<= 1) loss += __shfl_xor(loss, off, 64);
  __shared__ float ssum[4];
  if ((threadIdx.x & 63) == 0) ssum[threadIdx.x >> 6] = loss;
  __syncthreads();
  if (threadIdx.x == 0)
    atomicAdd(out, (ssum[0] + ssum[1] + ssum[2] + ssum[3]) / (float)B);
}

extern "C" void kernel_launch(void* const* d_in, const int* in_sizes, int n_in,
                              void* d_out, int out_size, void* d_ws, size_t ws_size,
                              hipStream_t stream) {
  const float* a      = (const float*)d_in[0];
  const float* b      = (const float*)d_in[1];
  const int*   labels = (const int*)d_in[2];
  const int B = in_sizes[2];
  const int D = in_sizes[0] / B;       // 256
  const int Tr = (B / BN) * 4;         // 256 row partial slots
  const int Tc = 4;                    // 4 col partial slots

  char* ws = (char*)d_ws;
  unsigned char* an = (unsigned char*)ws;                    // B*D fp8
  unsigned char* bn = (unsigned char*)(ws + (size_t)B * D);  // B*D fp8
  float* diag     = (float*)(ws + (size_t)2 * B * D);        // B*4
  float* row_part = diag + B;                                // Tr*B*4
  float* col_part = row_part + (size_t)Tr * B;               // Tc*B*4

  norm_kernel<<<B / 4, 256, 0, stream>>>(a, b, (unsigned int*)an,
                                         (unsigned int*)bn, diag,
                                         (float*)d_out, D);

  gemm_max_kernel<<<(B / BM) * (B / BN) / 16, 512, 0, stream>>>(
      an, bn, labels, row_part, col_part, B);

  finalize_kernel<<<(2 * B) / 256, 256, 0, stream>>>(
      row_part, col_part, diag, B, Tr, Tc, (float*)d_out);
}

// Round 4
// 140.900 us; speedup vs baseline: 1.2923x; 1.2923x over previous
//
#include <hip/hip_runtime.h>
#include <stdint.h>

#define BM 128
#define BN 128
#define KD 256     // K dimension; kernel assumes 256, B=8192

typedef __attribute__((ext_vector_type(4))) float f32x4;
typedef __attribute__((ext_vector_type(4))) int   i32x4;
typedef __attribute__((ext_vector_type(8))) int   i32x8;

// Kernel 1: per-row normalize, convert to fp8 e4m3 (OCP HW cvt); fp32 diag.
// Lane l handles elements [4l, 4l+4). Also zeroes d_out.
__global__ __launch_bounds__(256) void norm_kernel(
    const float* __restrict__ a, const float* __restrict__ b,
    unsigned int* __restrict__ an, unsigned int* __restrict__ bn,
    float* __restrict__ diag, float* __restrict__ out, int D) {
  if (blockIdx.x == 0 && threadIdx.x == 0) out[0] = 0.f;
  const int row = blockIdx.x * 4 + (threadIdx.x >> 6);
  const int l = threadIdx.x & 63;
  const float4 av = ((const float4*)(a + (size_t)row * D))[l];
  const float4 bv = ((const float4*)(b + (size_t)row * D))[l];
  float ssa = av.x*av.x + av.y*av.y + av.z*av.z + av.w*av.w;
  float ssb = bv.x*bv.x + bv.y*bv.y + bv.z*bv.z + bv.w*bv.w;
  float dot = av.x*bv.x + av.y*bv.y + av.z*bv.z + av.w*bv.w;
  for (int off = 1; off < 64; off <<= 1) {
    ssa += __shfl_xor(ssa, off, 64);
    ssb += __shfl_xor(ssb, off, 64);
    dot += __shfl_xor(dot, off, 64);
  }
  const float inva = 1.0f / sqrtf(ssa);
  const float invb = 1.0f / sqrtf(ssb);
  if (l == 0) diag[row] = dot * inva * invb;
  int pa = 0, pb = 0;
  pa = __builtin_amdgcn_cvt_pk_fp8_f32(av.x * inva, av.y * inva, pa, 0);
  pa = __builtin_amdgcn_cvt_pk_fp8_f32(av.z * inva, av.w * inva, pa, 1);
  pb = __builtin_amdgcn_cvt_pk_fp8_f32(bv.x * invb, bv.y * invb, pb, 0);
  pb = __builtin_amdgcn_cvt_pk_fp8_f32(bv.z * invb, bv.w * invb, pb, 1);
  an[(size_t)row * (D / 4) + l] = (unsigned int)pa;
  bn[(size_t)row * (D / 4) + l] = (unsigned int)pb;
}

// Kernel 2: PERSISTENT fp8 GEMM+max, v2 (round-3 post-mortem fixes).
// Grid = 512 blocks (2/CU), 512 threads (8 waves). Block (g0,tj): tj fixed
// B-panel, 8 A-panels ti = g0 + 8k.
//  - B-panel lives in REGISTERS (bfr[2][2], 32 VGPR/lane; each wave only
//    needs its own 32 columns) -> no sB, LDS = 64KB A-dbuf + 4KB labels +
//    1KB col = 69KB -> 2 blocks/CU; blocks ping-pong so one block's
//    vmcnt(0)+barrier drain hides under the other's compute.
//  - A-row labels for all 8 panels staged to LDS once (4KB); per-tile label
//    reads are broadcast ds_reads (lgkm), NOT global loads in the drain path.
//  - 8 iterations/block (vs 16): half the barrier-drain events of r3.
// XOR swizzle (proven r0 scheme): stored chunk of src chunk c, row r =
// ((c&7)^(r&7))|(c&8), applied on the global source; reads at p0/p1 undo it.
__global__ __launch_bounds__(512, 4) void gemm_max_kernel(
    const unsigned char* __restrict__ an, const unsigned char* __restrict__ bn,
    const int* __restrict__ labels,
    float* __restrict__ row_part, float* __restrict__ col_part, int B) {
  __shared__ __align__(16) unsigned char sA[2][BM * KD];  // 64 KB dbuf
  __shared__ int lds_lab[8 * BM];                         // 4 KB: A labels
  __shared__ float lds_col[2][BN];                        // 1 KB

  const int tid  = threadIdx.x;
  const int lane = tid & 63;
  const int w    = tid >> 6;            // 0..7
  const int wm   = w >> 2, wn = w & 3;  // 2 x 4 wave grid (64 rows x 32 cols)
  const int g0   = blockIdx.x >> 6;     // 0..7 : ti = g0 + 8k
  const int tj   = blockIdx.x & 63;     // fixed B-panel

  // staging decomposition
  const int sr = lane >> 4;             // row within 4-row group
  const int sc = lane & 15;             // dest 16B-chunk position
  // fragment decomposition
  const int fr = lane & 15;             // m/n index
  const int hi = lane >> 4;             // k-quad
  const int p0 = ((2 * hi)     ^ (fr & 7)) * 16;
  const int p1 = ((2 * hi + 1) ^ (fr & 7)) * 16;

  // ---- A-panel stage (32 KB, 4 passes x 8 waves x 4 rows) ----
  auto stage = [&](int bsel, int k) {
    const int ti = g0 + 8 * k;
    #pragma unroll
    for (int pass = 0; pass < 4; ++pass) {
      const int r0  = pass * 32 + w * 4;
      const int row = r0 + sr;
      const int g = ((sc & 7) ^ (row & 7)) | (sc & 8);
      const unsigned char* ga = an + (size_t)(ti * BM + row) * KD + g * 16;
      __builtin_amdgcn_global_load_lds(
          (const __attribute__((address_space(1))) void*)ga,
          (__attribute__((address_space(3))) void*)(&sA[bsel][r0 * KD + lane * 16]),
          16, 0, 0);
    }
  };

  // ---- Prologue: stage A panel 0 + all A labels; B-frags + col labels to regs ----
  stage(0, 0);
  #pragma unroll
  for (int h = 0; h < 2; ++h) {
    const int i = h * 512 + tid;        // 0..1023 : lds_lab[i] = labels[row(i)]
    const int* gl = labels + g0 * 128 + (i >> 7) * 1024 + (i & 127);
    __builtin_amdgcn_global_load_lds(
        (const __attribute__((address_space(1))) void*)gl,
        (__attribute__((address_space(3))) void*)(&lds_lab[h * 512 + w * 64 + lane]),
        4, 0, 0);
  }
  i32x8 bfr[2][2];
  #pragma unroll
  for (int it = 0; it < 2; ++it)
    #pragma unroll
    for (int nt = 0; nt < 2; ++nt) {
      const unsigned char* gb =
          bn + (size_t)(tj * BN + wn * 32 + nt * 16 + fr) * KD + it * 128 + hi * 32;
      bfr[it][nt] = __builtin_shufflevector(*(const i32x4*)gb,
                                            *(const i32x4*)(gb + 16),
                                            0, 1, 2, 3, 4, 5, 6, 7);
    }
  const int labc0 = labels[tj * BN + wn * 32 + fr];
  const int labc1 = labels[tj * BN + wn * 32 + 16 + fr];
  __syncthreads();   // A panel 0 + labels landed

  const int SC = 0x7F7F7F7F;            // E8M0 = 1.0 in all byte slots
  float cp0 = -1e9f, cp1 = -1e9f;       // col partials, live across all k

  #pragma unroll
  for (int k = 0; k < 8; ++k) {
    if (k < 7) stage((k + 1) & 1, k + 1);   // prefetch next panel (other buf)

    // ---- Compute: 16 MFMAs from sA[k&1] x B-regs ----
    f32x4 acc[4][2];
    #pragma unroll
    for (int mt = 0; mt < 4; ++mt) {
      acc[mt][0] = (f32x4){0.f, 0.f, 0.f, 0.f};
      acc[mt][1] = (f32x4){0.f, 0.f, 0.f, 0.f};
    }
    const unsigned char* Ab = sA[k & 1];
    #pragma unroll
    for (int it = 0; it < 2; ++it)
      #pragma unroll
      for (int mt = 0; mt < 4; ++mt) {
        const unsigned char* ra = Ab + (wm * 64 + mt * 16 + fr) * KD + it * 128;
        i32x8 af = __builtin_shufflevector(*(const i32x4*)(ra + p0),
                                           *(const i32x4*)(ra + p1),
                                           0, 1, 2, 3, 4, 5, 6, 7);
        acc[mt][0] = __builtin_amdgcn_mfma_scale_f32_16x16x128_f8f6f4(
            af, bfr[it][0], acc[mt][0], 0, 0, 0, SC, 0, SC);
        acc[mt][1] = __builtin_amdgcn_mfma_scale_f32_16x16x128_f8f6f4(
            af, bfr[it][1], acc[mt][1], 0, 0, 0, SC, 0, SC);
      }

    // ---- Per-tile epilogue (labels from LDS; no global loads) ----
    const size_t rowbase =
        (size_t)(tj * 4 + wn) * B + (size_t)(g0 + 8 * k) * BM + wm * 64;
    #pragma unroll
    for (int mt = 0; mt < 4; ++mt) {
      const i32x4 lv = *(const i32x4*)&lds_lab[k * 128 + wm * 64 + mt * 16 + hi * 4];
      float rr4[4];
      #pragma unroll
      for (int r = 0; r < 4; ++r) {
        const int l0 = lv[r];
        const float vm0 = (l0 != labc0) ? acc[mt][0][r] : -1e9f;
        const float vm1 = (l0 != labc1) ? acc[mt][1][r] : -1e9f;
        cp0 = fmaxf(cp0, vm0);
        cp1 = fmaxf(cp1, vm1);
        float rm = fmaxf(vm0, vm1);
        rm = fmaxf(rm, __shfl_xor(rm, 1, 64));
        rm = fmaxf(rm, __shfl_xor(rm, 2, 64));
        rm = fmaxf(rm, __shfl_xor(rm, 4, 64));
        rm = fmaxf(rm, __shfl_xor(rm, 8, 64));
        rr4[r] = rm;
      }
      if (fr == mt) {
        f32x4 v = {rr4[0], rr4[1], rr4[2], rr4[3]};
        *(f32x4*)(row_part + rowbase + mt * 16 + hi * 4) = v;
      }
    }

    __syncthreads();   // next panel staged; all waves done with sA[k&1]
  }

  // ---- Col partials: reduce across hi lanes, then across wm via LDS ----
  float c0 = fmaxf(cp0, __shfl_xor(cp0, 16, 64));
  c0 = fmaxf(c0, __shfl_xor(c0, 32, 64));
  float c1 = fmaxf(cp1, __shfl_xor(cp1, 16, 64));
  c1 = fmaxf(c1, __shfl_xor(c1, 32, 64));
  if (hi == 0) {
    lds_col[wm][wn * 32 + fr] = c0;
    lds_col[wm][wn * 32 + 16 + fr] = c1;
  }
  __syncthreads();
  if (tid < BN)
    col_part[(size_t)g0 * B + tj * BN + tid] =
        fmaxf(lds_col[0][tid], lds_col[1][tid]);
}

// Kernel 3: reduce per-slot maxes -> M; threshold; per-row loss; atomicAdd.
// Row dir: Tr=256 slots; col dir: Tc=8. Wave-per-quarter split for 4x the
// load parallelism (grid = 2B/64 = 256 blocks).
__global__ __launch_bounds__(256) void finalize_kernel(
    const float* __restrict__ row_part, const float* __restrict__ col_part,
    const float* __restrict__ diag, int B, int Tr, int Tc,
    float* __restrict__ out) {
  const int ln = threadIdx.x & 63;
  const int q  = threadIdx.x >> 6;           // wave = quarter of the T range
  const int item = blockIdx.x * 64 + ln;     // 0..2B-1
  const bool isrow = item < B;
  const int i = isrow ? item : item - B;
  const float* part = isrow ? row_part : col_part;
  const int T = isrow ? Tr : Tc;
  const int tpq = (T + 3) >> 2;
  const int t1 = min(T, (q + 1) * tpq);
  float m = -1e9f;
  for (int t = q * tpq; t < t1; ++t) m = fmaxf(m, part[(size_t)t * B + i]);
  __shared__ float smq[4][64];
  smq[q][ln] = m;
  __syncthreads();
  if (q == 0) {
    m = fmaxf(fmaxf(smq[0][ln], smq[1][ln]), fmaxf(smq[2][ln], smq[3][ln]));
    const float d = diag[i];
    float loss = 0.f;
    if ((d < 1.0f - 1e-5f) && (m + 0.2f > d)) {
      loss = fmaxf(0.2f * d * d - 0.7f * d + 0.5f, 0.f) +
             fmaxf(0.9f * m * m - 0.4f * m + 0.03f, 0.f);
    }
    for (int off = 1; off < 64; off <<= 1) loss += __shfl_xor(loss, off, 64);
    if (ln == 0) atomicAdd(out, loss / (float)B);
  }
}

extern "C" void kernel_launch(void* const* d_in, const int* in_sizes, int n_in,
                              void* d_out, int out_size, void* d_ws, size_t ws_size,
                              hipStream_t stream) {
  const float* a      = (const float*)d_in[0];
  const float* b      = (const float*)d_in[1];
  const int*   labels = (const int*)d_in[2];
  const int B = in_sizes[2];
  const int D = in_sizes[0] / B;       // 256
  const int Tr = (B / BN) * 4;         // 256 row partial slots (tj x wn)
  const int Tc = 8;                    // 8 col partial slots (g0)

  char* ws = (char*)d_ws;
  unsigned char* an = (unsigned char*)ws;                    // B*D fp8
  unsigned char* bn = (unsigned char*)(ws + (size_t)B * D);  // B*D fp8
  float* diag     = (float*)(ws + (size_t)2 * B * D);        // B*4
  float* row_part = diag + B;                                // Tr*B*4
  float* col_part = row_part + (size_t)Tr * B;               // Tc*B*4

  norm_kernel<<<B / 4, 256, 0, stream>>>(a, b, (unsigned int*)an,
                                         (unsigned int*)bn, diag,
                                         (float*)d_out, D);

  gemm_max_kernel<<<(B / BM) / 8 * (B / BN), 512, 0, stream>>>(
      an, bn, labels, row_part, col_part, B);

  finalize_kernel<<<(2 * B) / 64, 256, 0, stream>>>(
      row_part, col_part, diag, B, Tr, Tc, (float*)d_out);
}